// Round 13
// baseline (2741.187 us; speedup 1.0000x reference)
//
#include <hip/hip_runtime.h>
#include <stdint.h>

#define B_ 64
#define T_ 512
#define IN_ 128
#define H_ 256
#define G_ 768
#define M0_ (B_*T_)   // 32768

typedef _Float16 f16;
typedef _Float16 f16x2 __attribute__((ext_vector_type(2)));
typedef _Float16 half8 __attribute__((ext_vector_type(8)));
typedef float f32x4 __attribute__((ext_vector_type(4)));

#if __has_builtin(__builtin_amdgcn_fdot2)
__device__ inline float fdot2f(f16x2 a, f16x2 b, float c){ return __builtin_amdgcn_fdot2(a, b, c, false); }
#else
__device__ inline float fdot2f(f16x2 a, f16x2 b, float c){ return c + (float)a.x*(float)b.x + (float)a.y*(float)b.y; }
#endif

// ---------------- projection GEMM: xg[dir][m][n] = A[m][:]·W[dir][n][:] + bias[dir][n] ----------------
// A: M0 x K (f32 if AF32 else f16) row-major; W: 2 x 768 x K f32 (B^T layout); out: 2 x M0 x 768 f16
template<bool AF32>
__global__ __launch_bounds__(256) void k_proj(
    const float* __restrict__ Af, const f16* __restrict__ Ah,
    const float* __restrict__ W, const float* __restrict__ bias,
    f16* __restrict__ out, int K)
{
  int dir = blockIdx.z;
  const float* Wd = W + (size_t)dir*G_*K;
  const float* bd = bias + dir*G_;
  f16* outd = out + (size_t)dir*M0_*G_;
  int m0 = blockIdx.x*128, n0 = blockIdx.y*128;
  int tid = threadIdx.x, lane = tid & 63, wv = tid >> 6;
  int wm = wv >> 1, wn = wv & 1;
  int l15 = lane & 15, quad = lane >> 4;

  __shared__ f16 As[128][72];   // +8 pad breaks bank conflicts
  __shared__ f16 Ws[128][72];

  f32x4 acc[4][4];
  #pragma unroll
  for (int i = 0; i < 4; i++)
    #pragma unroll
    for (int j = 0; j < 4; j++) acc[i][j] = (f32x4){0.f,0.f,0.f,0.f};

  int lr = tid >> 3, lk = (tid & 7) * 8;
  for (int k0 = 0; k0 < K; k0 += 64){
    #pragma unroll
    for (int it = 0; it < 4; it++){
      int row = lr + it*32;
      // A tile
      if (AF32){
        const float* p = &Af[(size_t)(m0+row)*K + k0 + lk];
        float4 v0 = *(const float4*)p;
        float4 v1 = *(const float4*)(p + 4);
        *(half8*)&As[row][lk] = (half8){(f16)v0.x,(f16)v0.y,(f16)v0.z,(f16)v0.w,
                                        (f16)v1.x,(f16)v1.y,(f16)v1.z,(f16)v1.w};
      } else {
        *(uint4*)&As[row][lk] = *(const uint4*)&Ah[(size_t)(m0+row)*K + k0 + lk];
      }
      // W tile (always f32 -> f16)
      {
        const float* p = &Wd[(size_t)(n0+row)*K + k0 + lk];
        float4 v0 = *(const float4*)p;
        float4 v1 = *(const float4*)(p + 4);
        *(half8*)&Ws[row][lk] = (half8){(f16)v0.x,(f16)v0.y,(f16)v0.z,(f16)v0.w,
                                        (f16)v1.x,(f16)v1.y,(f16)v1.z,(f16)v1.w};
      }
    }
    __syncthreads();
    #pragma unroll
    for (int kk = 0; kk < 64; kk += 32){
      half8 af[4], bf[4];
      #pragma unroll
      for (int mi = 0; mi < 4; mi++) af[mi] = *(const half8*)&As[wm*64 + mi*16 + l15][kk + quad*8];
      #pragma unroll
      for (int ni = 0; ni < 4; ni++) bf[ni] = *(const half8*)&Ws[wn*64 + ni*16 + l15][kk + quad*8];
      #pragma unroll
      for (int mi = 0; mi < 4; mi++)
        #pragma unroll
        for (int ni = 0; ni < 4; ni++)
          acc[mi][ni] = __builtin_amdgcn_mfma_f32_16x16x32_f16(af[mi], bf[ni], acc[mi][ni], 0, 0, 0);
    }
    __syncthreads();
  }
  #pragma unroll
  for (int mi = 0; mi < 4; mi++){
    #pragma unroll
    for (int ni = 0; ni < 4; ni++){
      int m = m0 + wm*64 + mi*16 + quad*4;
      int n = n0 + wn*64 + ni*16 + l15;
      float bn = bd[n];
      #pragma unroll
      for (int r = 0; r < 4; r++)
        outd[(size_t)(m+r)*G_ + n] = (f16)(acc[mi][ni][r] + bn);
    }
  }
}

// ---------------- persistent-register GRU, fdot2 engine v4: 16 waves / 96 weight-regs ----------------
// VALU floor = 768 cyc/step/CU vs broadcast-M MFMA's 1862 (r12 measured ~59% MfmaUtil on
// active CUs = at that floor). Three prior fdot2 attempts died on the 128-arch-VGPR cap at
// >=2 waves/EU with 192 weight regs/lane. Fix: 16 waves (1024 thr) -> weight file divides
// to 98304 f16x2 / 1024 lanes = 96 regs/lane <= 128 @ waves_per_eu(4,4).
// Wave wv owns 16 COMPLETE units [wv*16, wv*16+16) (all 3 gate rows). Lane (i=lane&15 ->
// unit, q=lane>>4 -> 64-k quarter) holds 3 rows x 32 f16x2 = 96 regs. Per step: 96 fdot2,
// butterfly over lane bits 4,5 -> unit i's r/z/n fully lane-local (r7's proven topology,
// no hg round-trip). 4 waves/SIMD: LDS h reads are 16-lane same-address broadcasts; exp /
// barrier tails hide under co-waves. Live set ~122 <= 128.
// Single xg register set reloaded right after consumption (load->use = full step);
// one raw lgkm-only barrier/step; x2-unrolled ping-pong LDS h buffers; LASTL store elision.
template<bool LASTL>
__global__ __launch_bounds__(1024) __attribute__((amdgpu_waves_per_eu(4, 4)))
void k_rnn(
    const f16* __restrict__ xg, const float* __restrict__ whh,
    const float* __restrict__ bhh, f16* __restrict__ y)
{
  int b = blockIdx.x, dir = blockIdx.y;
  int tid = threadIdx.x, lane = tid & 63, wv = tid >> 6;   // wv < 16
  int i = lane & 15, q = lane >> 4;                        // unit sub-index, k-quarter
  int u = wv*16 + i;                                       // owned unit (4 lanes/unit)

  const f16* cxg = xg + ((size_t)dir*M0_ + (size_t)b*T_)*G_;
  const float* wbase = whh + (size_t)dir*G_*H_;
  const float* bh = bhh + dir*G_;
  f16* yb = y + (size_t)b*T_*512 + dir*256;

  __shared__ __align__(16) f16 h0buf[256];
  __shared__ __align__(16) f16 h1buf[256];

  // resident weights: wf[g*32 + j] = {W[g*256+u][q*64+2j], W[g*256+u][q*64+2j+1]}
  f16x2 wf[96];
  #pragma unroll
  for (int g = 0; g < 3; g++){
    const float* wrow = wbase + (size_t)(g*256 + u)*H_ + q*64;
    #pragma unroll
    for (int j = 0; j < 16; j++){
      float4 v = ((const float4*)wrow)[j];
      wf[g*32 + j*2 + 0] = (f16x2){(f16)v.x, (f16)v.y};
      wf[g*32 + j*2 + 1] = (f16x2){(f16)v.z, (f16)v.w};
    }
  }

  float br = bh[u], bz = bh[u+256], bn = bh[u+512];
  float hreg = 0.f;
  if (tid < 256) h0buf[tid] = (f16)0.f;
  __syncthreads();

  // single xg register set; prologue loads step 0 (declared before use)
  f16 axr, axz, axn;
  {
    int t0 = dir ? (T_-1) : 0;
    const f16* xp = cxg + (size_t)t0*G_ + u;
    axr = xp[0]; axz = xp[256]; axn = xp[512];
  }

// TT: this step's time index (store); TN: next step's (xg reload)
#define RSTEP(SRC, DST, TT, TN)                                                 \
  {                                                                             \
    const half8* hp = (const half8*)&SRC[q*64];                                 \
    float ac0 = 0.f, ac1 = 0.f, ac2 = 0.f;                                      \
    half8 hcur = hp[0];                                                         \
    half8 hnxt = hp[1];                                                         \
    _Pragma("unroll")                                                           \
    for (int s2 = 0; s2 < 8; s2++){                                             \
      half8 hh = hcur;                                                          \
      hcur = hnxt;                                                              \
      if (s2 < 6) hnxt = hp[s2+2];                                              \
      _Pragma("unroll")                                                         \
      for (int e = 0; e < 4; e++){                                              \
        f16x2 pp = {hh[2*e], hh[2*e+1]};                                        \
        ac0 = fdot2f(wf[ 0 + s2*4 + e], pp, ac0);                               \
        ac1 = fdot2f(wf[32 + s2*4 + e], pp, ac1);                               \
        ac2 = fdot2f(wf[64 + s2*4 + e], pp, ac2);                               \
      }                                                                         \
    }                                                                           \
    ac0 += __shfl_xor(ac0, 16); ac0 += __shfl_xor(ac0, 32);                     \
    ac1 += __shfl_xor(ac1, 16); ac1 += __shfl_xor(ac1, 32);                     \
    ac2 += __shfl_xor(ac2, 16); ac2 += __shfl_xor(ac2, 32);                     \
    float ar = (float)axr + ac0 + br; ar = fminf(fmaxf(ar, -30.f), 30.f);       \
    float az = (float)axz + ac1 + bz; az = fminf(fmaxf(az, -30.f), 30.f);       \
    float r_ = 1.f/(1.f + __expf(-ar));                                         \
    float z_ = 1.f/(1.f + __expf(-az));                                         \
    float an = (float)axn + r_*(ac2 + bn); an = fminf(fmaxf(an, -15.f), 15.f);  \
    float e_ = __expf(2.f*an);                                                  \
    float nn = (e_ - 1.f)/(e_ + 1.f);                                           \
    hreg = (1.f - z_)*nn + z_*hreg;                                             \
    if (lane < 16){                                                             \
      DST[u] = (f16)hreg;                                                       \
      if (!LASTL || (TT) == T_-1)                                               \
        yb[(size_t)(TT)*512 + u] = (f16)hreg;                                   \
    }                                                                           \
    {   /* reload xg for the NEXT step (consumed a full step from now) */       \
      const f16* xq = cxg + (size_t)(TN)*G_ + u;                                \
      axr = xq[0]; axz = xq[256]; axn = xq[512];                                \
    }                                                                           \
    asm volatile("s_waitcnt lgkmcnt(0)\n\ts_barrier" ::: "memory");             \
  }

  for (int s = 0; s < T_; s += 2){
    int ttA = dir ? (T_-1-s) : s;
    int ttB = dir ? (T_-2-s) : (s+1);
    int s2c = (s + 2 < T_) ? (s + 2) : (T_ - 1);   // clamped dummy on last iter
    int ttC = dir ? (T_-1-s2c) : s2c;

    RSTEP(h0buf, h1buf, ttA, ttB)
    RSTEP(h1buf, h0buf, ttB, ttC)
  }
#undef RSTEP
}

// ---------------- MLP head: one WG per batch, all f32 ----------------
__global__ __launch_bounds__(256) void k_head(
    const f16* __restrict__ y,
    const float* __restrict__ W1, const float* __restrict__ b1,
    const float* __restrict__ W2, const float* __restrict__ b2,
    const float* __restrict__ W3, const float* __restrict__ b3,
    const float* __restrict__ W4, const float* __restrict__ b4,
    float* __restrict__ out)
{
  int b = blockIdx.x, tid = threadIdx.x;
  __shared__ float a0[512], a1[128], a2[64], a3[256];
  const f16* yr = y + ((size_t)b*T_ + (T_-1))*512;
  a0[tid] = (float)yr[tid]; a0[tid+256] = (float)yr[tid+256];
  __syncthreads();
  if (tid < 128){
    float s = b1[tid];
    const float4* w = (const float4*)(W1 + (size_t)tid*512);
    #pragma unroll 8
    for (int c = 0; c < 128; c++){
      float4 v = w[c];
      s += v.x*a0[c*4] + v.y*a0[c*4+1] + v.z*a0[c*4+2] + v.w*a0[c*4+3];
    }
    a1[tid] = fmaxf(s, 0.f);
  }
  __syncthreads();
  if (tid < 64){
    float s = b2[tid];
    const float4* w = (const float4*)(W2 + (size_t)tid*128);
    #pragma unroll
    for (int c = 0; c < 32; c++){
      float4 v = w[c];
      s += v.x*a1[c*4] + v.y*a1[c*4+1] + v.z*a1[c*4+2] + v.w*a1[c*4+3];
    }
    a2[tid] = fmaxf(s, 0.f);
  }
  __syncthreads();
  if (tid < 256){
    float s = b3[tid];
    const float4* w = (const float4*)(W3 + (size_t)tid*64);
    #pragma unroll
    for (int c = 0; c < 16; c++){
      float4 v = w[c];
      s += v.x*a2[c*4] + v.y*a2[c*4+1] + v.z*a2[c*4+2] + v.w*a2[c*4+3];
    }
    a3[tid] = fmaxf(s, 0.f);
  }
  __syncthreads();
  if (tid < 50){
    float s = b4[tid];
    const float4* w = (const float4*)(W4 + (size_t)tid*256);
    #pragma unroll
    for (int c = 0; c < 64; c++){
      float4 v = w[c];
      s += v.x*a3[c*4] + v.y*a3[c*4+1] + v.z*a3[c*4+2] + v.w*a3[c*4+3];
    }
    out[b*50 + tid] = s;
  }
}

extern "C" void kernel_launch(void* const* d_in, const int* in_sizes, int n_in,
                              void* d_out, int out_size, void* d_ws, size_t ws_size,
                              hipStream_t stream)
{
  const float* x    = (const float*)d_in[0];
  const float* Wih0 = (const float*)d_in[1];
  const float* Whh0 = (const float*)d_in[2];
  const float* bih0 = (const float*)d_in[3];
  const float* bhh0 = (const float*)d_in[4];
  const float* Wih  = (const float*)d_in[5];
  const float* Whh  = (const float*)d_in[6];
  const float* bih  = (const float*)d_in[7];
  const float* bhh  = (const float*)d_in[8];
  const float* W1 = (const float*)d_in[9];
  const float* b1 = (const float*)d_in[10];
  const float* W2 = (const float*)d_in[11];
  const float* b2 = (const float*)d_in[12];
  const float* W3 = (const float*)d_in[13];
  const float* b3 = (const float*)d_in[14];
  const float* W4 = (const float*)d_in[15];
  const float* b4 = (const float*)d_in[16];

  char* ws = (char*)d_ws;
  f16* xg = (f16*)ws;                          // 2*M0*768*2 = 100,663,296 B
  f16* y  = (f16*)(ws + 100663296ull);         //   M0*512*2 =  33,554,432 B
  // total exactly 128 MiB; nothing written beyond.

  // layer 0 (A = x, f32, K=128)
  k_proj<true >  <<<dim3(M0_/128, 6, 2), dim3(256),  0, stream>>>(x, nullptr, Wih0, bih0, xg, IN_);
  k_rnn<false>   <<<dim3(B_, 2),         dim3(1024), 0, stream>>>(xg, Whh0, bhh0, y);
  // layer 1 (A = y, f16, K=512)
  k_proj<false>  <<<dim3(M0_/128, 6, 2), dim3(256),  0, stream>>>(nullptr, y, Wih, bih, xg, 2*H_);
  k_rnn<false>   <<<dim3(B_, 2),         dim3(1024), 0, stream>>>(xg, Whh, bhh, y);
  // layer 2 (y stores elided except tt == T-1; k_head reads only y[:,T-1,:])
  k_proj<false>  <<<dim3(M0_/128, 6, 2), dim3(256),  0, stream>>>(nullptr, y, Wih + 1ull*2*G_*(2*H_), bih + 2*G_, xg, 2*H_);
  k_rnn<true>    <<<dim3(B_, 2),         dim3(1024), 0, stream>>>(xg, Whh + 1ull*2*G_*H_, bhh + 2*G_, y);

  k_head<<<dim3(B_), dim3(256), 0, stream>>>(y, W1, b1, W2, b2, W3, b3, W4, b4,
                                             (float*)d_out);
}

// Round 14
// 1983.521 us; speedup vs baseline: 1.3820x; 1.3820x over previous
//
#include <hip/hip_runtime.h>
#include <stdint.h>

#define B_ 64
#define T_ 512
#define IN_ 128
#define H_ 256
#define G_ 768
#define M0_ (B_*T_)   // 32768

typedef _Float16 f16;
typedef _Float16 f16x2 __attribute__((ext_vector_type(2)));
typedef _Float16 half8 __attribute__((ext_vector_type(8)));
typedef float f32x4 __attribute__((ext_vector_type(4)));

// ---------------- projection GEMM: xg[dir][m][n] = A[m][:]·W[dir][n][:] + bias[dir][n] ----------------
// A: M0 x K (f32 if AF32 else f16) row-major; W: 2 x 768 x K f32 (B^T layout); out: 2 x M0 x 768 f16
template<bool AF32>
__global__ __launch_bounds__(256) void k_proj(
    const float* __restrict__ Af, const f16* __restrict__ Ah,
    const float* __restrict__ W, const float* __restrict__ bias,
    f16* __restrict__ out, int K)
{
  int dir = blockIdx.z;
  const float* Wd = W + (size_t)dir*G_*K;
  const float* bd = bias + dir*G_;
  f16* outd = out + (size_t)dir*M0_*G_;
  int m0 = blockIdx.x*128, n0 = blockIdx.y*128;
  int tid = threadIdx.x, lane = tid & 63, wv = tid >> 6;
  int wm = wv >> 1, wn = wv & 1;
  int l15 = lane & 15, quad = lane >> 4;

  __shared__ f16 As[128][72];   // +8 pad breaks bank conflicts
  __shared__ f16 Ws[128][72];

  f32x4 acc[4][4];
  #pragma unroll
  for (int i = 0; i < 4; i++)
    #pragma unroll
    for (int j = 0; j < 4; j++) acc[i][j] = (f32x4){0.f,0.f,0.f,0.f};

  int lr = tid >> 3, lk = (tid & 7) * 8;
  for (int k0 = 0; k0 < K; k0 += 64){
    #pragma unroll
    for (int it = 0; it < 4; it++){
      int row = lr + it*32;
      // A tile
      if (AF32){
        const float* p = &Af[(size_t)(m0+row)*K + k0 + lk];
        float4 v0 = *(const float4*)p;
        float4 v1 = *(const float4*)(p + 4);
        *(half8*)&As[row][lk] = (half8){(f16)v0.x,(f16)v0.y,(f16)v0.z,(f16)v0.w,
                                        (f16)v1.x,(f16)v1.y,(f16)v1.z,(f16)v1.w};
      } else {
        *(uint4*)&As[row][lk] = *(const uint4*)&Ah[(size_t)(m0+row)*K + k0 + lk];
      }
      // W tile (always f32 -> f16)
      {
        const float* p = &Wd[(size_t)(n0+row)*K + k0 + lk];
        float4 v0 = *(const float4*)p;
        float4 v1 = *(const float4*)(p + 4);
        *(half8*)&Ws[row][lk] = (half8){(f16)v0.x,(f16)v0.y,(f16)v0.z,(f16)v0.w,
                                        (f16)v1.x,(f16)v1.y,(f16)v1.z,(f16)v1.w};
      }
    }
    __syncthreads();
    #pragma unroll
    for (int kk = 0; kk < 64; kk += 32){
      half8 af[4], bf[4];
      #pragma unroll
      for (int mi = 0; mi < 4; mi++) af[mi] = *(const half8*)&As[wm*64 + mi*16 + l15][kk + quad*8];
      #pragma unroll
      for (int ni = 0; ni < 4; ni++) bf[ni] = *(const half8*)&Ws[wn*64 + ni*16 + l15][kk + quad*8];
      #pragma unroll
      for (int mi = 0; mi < 4; mi++)
        #pragma unroll
        for (int ni = 0; ni < 4; ni++)
          acc[mi][ni] = __builtin_amdgcn_mfma_f32_16x16x32_f16(af[mi], bf[ni], acc[mi][ni], 0, 0, 0);
    }
    __syncthreads();
  }
  #pragma unroll
  for (int mi = 0; mi < 4; mi++){
    #pragma unroll
    for (int ni = 0; ni < 4; ni++){
      int m = m0 + wm*64 + mi*16 + quad*4;
      int n = n0 + wn*64 + ni*16 + l15;
      float bn = bd[n];
      #pragma unroll
      for (int r = 0; r < 4; r++)
        outd[(size_t)(m+r)*G_ + n] = (f16)(acc[mi][ni][r] + bn);
    }
  }
}

// ---------------- persistent-register GRU via broadcast-M MFMA, 8 waves @ 2 waves/EU ----------------
// Measured optimum (r12: 1982.8 us total; k_rnn 570-585 us). Structure:
//   - Wave wv owns units [wv*32,wv*32+32): 6 tiles (3 gates x 2 col-tiles) x 8 k-frags
//     = 48 half8 B-frags (192 regs) resident in the AGPR side of the unified file
//     (waves_per_eu(2,2) pins the allocator; VGPR_Count=128 arch, no spill).
//   - Broadcast-M: every A-row of the 16x16x32 MFMA carries the same h slice -> lane's
//     acc[t][0] is the full 256-dot for its column; no cross-lane reduce.
//   - Ping-pong xg register sets via x2-unrolled step loop (load->use = full step).
//   - One raw lgkm-only barrier per step (vmem latency stays off the critical path).
//   - template<LASTL>: last layer stores y only at tt == T_-1 (k_head reads y[:,T-1,:]).
// Structural floor: 384 MFMA/CU/step x 4.85 cyc = 1862 cyc of the measured 2680 cyc/step
// (~59% MfmaUtil on the 128 active CUs). The VALU fdot2 alternative (768-cyc floor) is
// unreachable: the allocator never grants >=96 arch VGPRs at multi-wave occupancy
// (r0/r7/r9/r13), and v_dot2 cannot read AGPRs. Cross-sequence M-batching trades CU
// count 1:1 against MFMA efficiency (r10). This is the practical floor for this target.
template<bool LASTL>
__global__ __launch_bounds__(512) __attribute__((amdgpu_waves_per_eu(2, 2)))
void k_rnn(
    const f16* __restrict__ xg, const float* __restrict__ whh,
    const float* __restrict__ bhh, f16* __restrict__ y)
{
  int b = blockIdx.x, dir = blockIdx.y;
  int tid = threadIdx.x, lane = tid & 63, wv = tid >> 6;
  int col = lane & 15, kg = lane >> 4;       // fragment coords: col, k-group of 8
  int u = wv*32 + (lane & 31);               // owned unit (lanes 32-63 mirror 0-31)
  int dsel = (lane >> 4) & 1;                // col-tile select

  const f16* cxg = xg + ((size_t)dir*M0_ + (size_t)b*T_)*G_;
  const float* wbase = whh + (size_t)dir*G_*H_;
  const float* bh = bhh + dir*G_;
  f16* yb = y + (size_t)b*T_*512 + dir*256;

  __shared__ __align__(16) f16 h0buf[256];
  __shared__ __align__(16) f16 h1buf[256];

  // ---- resident B-fragments: tile t = gate*2 + coltile, 8 k-frags each ----
  half8 wf[48];
  #pragma unroll
  for (int t = 0; t < 6; t++){
    int g = t >> 1, c = t & 1;
    const float* wrow = wbase + (size_t)(g*256 + wv*32 + c*16 + col)*H_;
    #pragma unroll
    for (int kf = 0; kf < 8; kf++){
      const float4* p = (const float4*)(wrow + kf*32 + kg*8);
      float4 v0 = p[0], v1 = p[1];
      wf[t*8+kf] = (half8){(f16)v0.x,(f16)v0.y,(f16)v0.z,(f16)v0.w,
                           (f16)v1.x,(f16)v1.y,(f16)v1.z,(f16)v1.w};
    }
  }

  float br = bh[u], bz = bh[u+256], bn = bh[u+512];
  float hreg = 0.f;
  if (tid < 256) h0buf[tid] = (f16)0.f;
  __syncthreads();

  // ping-pong xg register sets (no rotate copies)
  f16 axr, axz, axn, bxr, bxz, bxn;
  {
    int t0 = dir ? (T_-1) : 0;
    const f16* xp = cxg + (size_t)t0*G_ + u;
    axr = xp[0]; axz = xp[256]; axn = xp[512];
  }

#define RSTEP(SRC, DST, XR, XZ, XN, TT)                                         \
  {                                                                             \
    const f16* hp = &SRC[kg*8];                                                 \
    f32x4 acc[6];                                                               \
    half8 acur = *(const half8*)hp;                                             \
    half8 anxt = *(const half8*)(hp + 32);                                      \
    _Pragma("unroll")                                                           \
    for (int kf = 0; kf < 8; kf++){                                             \
      half8 ac = acur;                                                          \
      acur = anxt;                                                              \
      if (kf < 6) anxt = *(const half8*)(hp + (kf+2)*32);                       \
      _Pragma("unroll")                                                         \
      for (int t = 0; t < 6; t++){                                              \
        if (kf == 0)                                                            \
          acc[t] = __builtin_amdgcn_mfma_f32_16x16x32_f16(ac, wf[t*8+kf],       \
                     (f32x4){0.f,0.f,0.f,0.f}, 0, 0, 0);                        \
        else                                                                    \
          acc[t] = __builtin_amdgcn_mfma_f32_16x16x32_f16(ac, wf[t*8+kf],       \
                     acc[t], 0, 0, 0);                                          \
      }                                                                         \
    }                                                                           \
    float sr = dsel ? acc[1][0] : acc[0][0];                                    \
    float sz = dsel ? acc[3][0] : acc[2][0];                                    \
    float sn = dsel ? acc[5][0] : acc[4][0];                                    \
    float ar = (float)(XR) + sr + br; ar = fminf(fmaxf(ar, -30.f), 30.f);       \
    float az = (float)(XZ) + sz + bz; az = fminf(fmaxf(az, -30.f), 30.f);       \
    float r_ = 1.f/(1.f + __expf(-ar));                                         \
    float z_ = 1.f/(1.f + __expf(-az));                                         \
    float an = (float)(XN) + r_*(sn + bn); an = fminf(fmaxf(an, -15.f), 15.f);  \
    float e_ = __expf(2.f*an);                                                  \
    float nn = (e_ - 1.f)/(e_ + 1.f);                                           \
    hreg = (1.f - z_)*nn + z_*hreg;                                             \
    if (lane < 32){                                                             \
      DST[u] = (f16)hreg;                                                       \
      if (!LASTL || (TT) == T_-1)                                               \
        yb[(size_t)(TT)*512 + u] = (f16)hreg;                                   \
    }                                                                           \
    asm volatile("s_waitcnt lgkmcnt(0)\n\ts_barrier" ::: "memory");             \
  }

  for (int s = 0; s < T_; s += 2){
    int ttA = dir ? (T_-1-s) : s;
    int ttB = dir ? (T_-2-s) : (s+1);
    int s2c = (s + 2 < T_) ? (s + 2) : (T_ - 1);   // clamped dummy on last iter
    int ttC = dir ? (T_-1-s2c) : s2c;

    // half A: prefetch set B (step s+1) BEFORE the body; body consumes set A
    {
      const f16* xq = cxg + (size_t)ttB*G_ + u;
      bxr = xq[0]; bxz = xq[256]; bxn = xq[512];
    }
    RSTEP(h0buf, h1buf, axr, axz, axn, ttA)

    // half B: prefetch set A (step s+2); body consumes set B
    {
      const f16* xq = cxg + (size_t)ttC*G_ + u;
      axr = xq[0]; axz = xq[256]; axn = xq[512];
    }
    RSTEP(h1buf, h0buf, bxr, bxz, bxn, ttB)
  }
#undef RSTEP
}

// ---------------- MLP head: one WG per batch, all f32 ----------------
__global__ __launch_bounds__(256) void k_head(
    const f16* __restrict__ y,
    const float* __restrict__ W1, const float* __restrict__ b1,
    const float* __restrict__ W2, const float* __restrict__ b2,
    const float* __restrict__ W3, const float* __restrict__ b3,
    const float* __restrict__ W4, const float* __restrict__ b4,
    float* __restrict__ out)
{
  int b = blockIdx.x, tid = threadIdx.x;
  __shared__ float a0[512], a1[128], a2[64], a3[256];
  const f16* yr = y + ((size_t)b*T_ + (T_-1))*512;
  a0[tid] = (float)yr[tid]; a0[tid+256] = (float)yr[tid+256];
  __syncthreads();
  if (tid < 128){
    float s = b1[tid];
    const float4* w = (const float4*)(W1 + (size_t)tid*512);
    #pragma unroll 8
    for (int c = 0; c < 128; c++){
      float4 v = w[c];
      s += v.x*a0[c*4] + v.y*a0[c*4+1] + v.z*a0[c*4+2] + v.w*a0[c*4+3];
    }
    a1[tid] = fmaxf(s, 0.f);
  }
  __syncthreads();
  if (tid < 64){
    float s = b2[tid];
    const float4* w = (const float4*)(W2 + (size_t)tid*128);
    #pragma unroll
    for (int c = 0; c < 32; c++){
      float4 v = w[c];
      s += v.x*a1[c*4] + v.y*a1[c*4+1] + v.z*a1[c*4+2] + v.w*a1[c*4+3];
    }
    a2[tid] = fmaxf(s, 0.f);
  }
  __syncthreads();
  if (tid < 256){
    float s = b3[tid];
    const float4* w = (const float4*)(W3 + (size_t)tid*64);
    #pragma unroll
    for (int c = 0; c < 16; c++){
      float4 v = w[c];
      s += v.x*a2[c*4] + v.y*a2[c*4+1] + v.z*a2[c*4+2] + v.w*a2[c*4+3];
    }
    a3[tid] = fmaxf(s, 0.f);
  }
  __syncthreads();
  if (tid < 50){
    float s = b4[tid];
    const float4* w = (const float4*)(W4 + (size_t)tid*256);
    #pragma unroll
    for (int c = 0; c < 64; c++){
      float4 v = w[c];
      s += v.x*a3[c*4] + v.y*a3[c*4+1] + v.z*a3[c*4+2] + v.w*a3[c*4+3];
    }
    out[b*50 + tid] = s;
  }
}

extern "C" void kernel_launch(void* const* d_in, const int* in_sizes, int n_in,
                              void* d_out, int out_size, void* d_ws, size_t ws_size,
                              hipStream_t stream)
{
  const float* x    = (const float*)d_in[0];
  const float* Wih0 = (const float*)d_in[1];
  const float* Whh0 = (const float*)d_in[2];
  const float* bih0 = (const float*)d_in[3];
  const float* bhh0 = (const float*)d_in[4];
  const float* Wih  = (const float*)d_in[5];
  const float* Whh  = (const float*)d_in[6];
  const float* bih  = (const float*)d_in[7];
  const float* bhh  = (const float*)d_in[8];
  const float* W1 = (const float*)d_in[9];
  const float* b1 = (const float*)d_in[10];
  const float* W2 = (const float*)d_in[11];
  const float* b2 = (const float*)d_in[12];
  const float* W3 = (const float*)d_in[13];
  const float* b3 = (const float*)d_in[14];
  const float* W4 = (const float*)d_in[15];
  const float* b4 = (const float*)d_in[16];

  char* ws = (char*)d_ws;
  f16* xg = (f16*)ws;                          // 2*M0*768*2 = 100,663,296 B
  f16* y  = (f16*)(ws + 100663296ull);         //   M0*512*2 =  33,554,432 B
  // total exactly 128 MiB; nothing written beyond.

  // layer 0 (A = x, f32, K=128)
  k_proj<true >  <<<dim3(M0_/128, 6, 2), dim3(256), 0, stream>>>(x, nullptr, Wih0, bih0, xg, IN_);
  k_rnn<false>   <<<dim3(B_, 2),         dim3(512), 0, stream>>>(xg, Whh0, bhh0, y);
  // layer 1 (A = y, f16, K=512)
  k_proj<false>  <<<dim3(M0_/128, 6, 2), dim3(256), 0, stream>>>(nullptr, y, Wih, bih, xg, 2*H_);
  k_rnn<false>   <<<dim3(B_, 2),         dim3(512), 0, stream>>>(xg, Whh, bhh, y);
  // layer 2 (y stores elided except tt == T-1; k_head reads only y[:,T-1,:])
  k_proj<false>  <<<dim3(M0_/128, 6, 2), dim3(256), 0, stream>>>(nullptr, y, Wih + 1ull*2*G_*(2*H_), bih + 2*G_, xg, 2*H_);
  k_rnn<true>    <<<dim3(B_, 2),         dim3(512), 0, stream>>>(xg, Whh + 1ull*2*G_*H_, bhh + 2*G_, y);

  k_head<<<dim3(B_), dim3(256), 0, stream>>>(y, W1, b1, W2, b2, W3, b3, W4, b4,
                                             (float*)d_out);
}